// Round 7
// baseline (254.171 us; speedup 1.0000x reference)
//
#include <hip/hip_runtime.h>
#include <math.h>

#define N_NODES 50000
#define N_EDGES 800000
#define DIM 128
#define NH 8
#define HD 16
#define CAP 64                                           // max degree capacity (Poisson λ=16; P(>64)~1e-24)
#define NGROUP_MAX (CAP / 8)                             // 8
#define N_RTILES (N_NODES / 16)                          // 3125
#define GEMM_BLOCKS ((N_RTILES + 7) / 8)                 // 391: 8 rt/block, 4 waves = (rt-group, ct-half)
#define SCAT_BLOCKS ((N_EDGES / 4 + 255) / 256)          // 782 (4 edges/thread, int4 loads)

typedef __attribute__((ext_vector_type(8))) short short8;
typedef __attribute__((ext_vector_type(8))) unsigned short ushort8v;
typedef __attribute__((ext_vector_type(4))) float floatx4;
typedef __attribute__((ext_vector_type(4))) int intx4;

// ---------- bf16 helpers ----------
__device__ __forceinline__ unsigned short f2bf(float f) {
    unsigned u = __float_as_uint(f);
    u += 0x7fffu + ((u >> 16) & 1u);        // round-to-nearest-even
    return (unsigned short)(u >> 16);
}
__device__ __forceinline__ float bf2f(unsigned short h) {
    return __uint_as_float((unsigned)h << 16);
}
__device__ __forceinline__ short8 pack_bf8(float4 lo, float4 hi) {
    short8 r;
    r[0] = (short)f2bf(lo.x); r[1] = (short)f2bf(lo.y);
    r[2] = (short)f2bf(lo.z); r[3] = (short)f2bf(lo.w);
    r[4] = (short)f2bf(hi.x); r[5] = (short)f2bf(hi.y);
    r[6] = (short)f2bf(hi.z); r[7] = (short)f2bf(hi.w);
    return r;
}

// ---------- K1: QKV MFMA GEMM (4 rt x 12 ct per wave, in-register W convert,
//              LDS-transposed full-line C stores)  ||  bucket scatter ----------
// Round-6 post-mortem: LDS C-flush fixed write amplification (gemm_scatter left
// top-5). Remaining gemm pole = per-wave serial chain (24 ct) x low wave count
// (784 waves, ~3/CU). Fix: split ct across 2 waves (chain 24->12) and 2x waves
// (1564). W is converted fp32->bf16 in-register at B-load time (same RNE f2bf,
// bitwise-identical output); per-ct matrix select is wave-uniform. This deletes
// prep_kernel entirely (cursor zero -> hipMemsetAsync).
__global__ __launch_bounds__(256) void gemm_scatter_kernel(
    const float* __restrict__ x,
    const float* __restrict__ WQ, const float* __restrict__ WK, const float* __restrict__ WV,
    const float* __restrict__ bQ, const float* __restrict__ bK, const float* __restrict__ bV,
    unsigned short* __restrict__ Qb, unsigned short* __restrict__ KVb,
    const int* __restrict__ ei, int* __restrict__ cursor, int2* __restrict__ slot2)
{
    __shared__ unsigned short cstage[4][64][72];          // 36 KB/block, per-wave private

    if ((int)blockIdx.x >= GEMM_BLOCKS) {
        const int e0 = ((blockIdx.x - GEMM_BLOCKS) * 256 + threadIdx.x) * 4;
        if (e0 >= N_EDGES) return;                        // E%4==0 -> int4 safe
        const intx4 s4 = __builtin_nontemporal_load((const intx4*)(ei + e0));
        const intx4 d4 = __builtin_nontemporal_load((const intx4*)(ei + N_EDGES + e0));
        #pragma unroll
        for (int k = 0; k < 4; ++k) {
            const int dd = d4[k];
            const int pos = atomicAdd(cursor + dd, 1);
            if (pos < CAP)
                slot2[(size_t)dd * CAP + pos] = make_int2(s4[k], e0 + k);
        }
        return;
    }

    const int wave = threadIdx.x >> 6;
    const int lane = threadIdx.x & 63;
    const int r    = lane & 15;
    const int quad = lane >> 4;
    const int rtg  = wave >> 1;                 // 0..1: row-tile group of 4
    const int half = wave & 1;                  // 0..1: ct-half (12 col-tiles)
    const int rt0  = blockIdx.x * 8 + rtg * 4;
    unsigned short (*cs)[72] = cstage[wave];

    short8 a[4][4];
    #pragma unroll
    for (int i = 0; i < 4; ++i) {
        int rt = rt0 + i; if (rt >= N_RTILES) rt = N_RTILES - 1;   // clamp (stores guarded)
        const float* xr = x + (size_t)(rt * 16 + r) * DIM + quad * 8;
        #pragma unroll
        for (int kk = 0; kk < 4; ++kk) {
            float4 lo = *(const float4*)(xr + kk * 32);
            float4 hi = *(const float4*)(xr + kk * 32 + 4);
            a[i][kk] = pack_bf8(lo, hi);
        }
    }

    const int chunk = lane & 7;                 // store-phase lane mapping
    const int rowg  = lane >> 3;

    for (int cg = 0; cg < 3; ++cg) {            // 3 groups of 4 col-tiles (64 cols)
        #pragma unroll
        for (int ci = 0; ci < 4; ++ci) {
            const int ct = half * 12 + cg * 4 + ci;            // 0..23 global col-tile
            const float* Wsrc; const float* bsrc;
            if (ct < 8)       { Wsrc = WQ; bsrc = bQ; }        // wave-uniform per ct
            else if (ct < 16) { Wsrc = WK; bsrc = bK; }
            else              { Wsrc = WV; bsrc = bV; }
            const int lr = ((ct & 7) * 16) + r;                // local row in W (0..127)
            const float* wr = Wsrc + (size_t)lr * DIM + quad * 8;
            short8 b0, b1, b2, b3;
            {
                float4 l0 = *(const float4*)(wr);      float4 h0 = *(const float4*)(wr + 4);
                float4 l1 = *(const float4*)(wr + 32); float4 h1 = *(const float4*)(wr + 36);
                float4 l2 = *(const float4*)(wr + 64); float4 h2 = *(const float4*)(wr + 68);
                float4 l3 = *(const float4*)(wr + 96); float4 h3 = *(const float4*)(wr + 100);
                b0 = pack_bf8(l0, h0); b1 = pack_bf8(l1, h1);
                b2 = pack_bf8(l2, h2); b3 = pack_bf8(l3, h3);
            }
            const float bias = bsrc[lr];

            #pragma unroll
            for (int i = 0; i < 4; ++i) {
                floatx4 c = {0.f, 0.f, 0.f, 0.f};
                c = __builtin_amdgcn_mfma_f32_16x16x32_bf16(a[i][0], b0, c, 0, 0, 0);
                c = __builtin_amdgcn_mfma_f32_16x16x32_bf16(a[i][1], b1, c, 0, 0, 0);
                c = __builtin_amdgcn_mfma_f32_16x16x32_bf16(a[i][2], b2, c, 0, 0, 0);
                c = __builtin_amdgcn_mfma_f32_16x16x32_bf16(a[i][3], b3, c, 0, 0, 0);
                #pragma unroll
                for (int rr = 0; rr < 4; ++rr)
                    cs[i * 16 + quad * 4 + rr][ci * 16 + r] = f2bf(c[rr] + bias);
            }
        }

        // ---- flush: 64 rows x 64 cols as row-major full-line stores ----
        const int g0col = half * 192 + cg * 64;   // 0,64->Q; 128,192->K; 256,320->V
        const int m = g0col >> 7;                 // 0=Q, 1=K, 2=V
        unsigned short* base;
        int stride, coff;
        if (m == 0) { base = Qb;  stride = DIM;     coff = g0col; }
        else        { base = KVb; stride = 2 * DIM; coff = (g0col & (DIM - 1)) + (m == 2 ? DIM : 0); }
        #pragma unroll
        for (int s = 0; s < 8; ++s) {
            const int rl = s * 8 + rowg;          // local row 0..63
            const int node = rt0 * 16 + rl;
            if (node < N_NODES) {
                const ushort8v v = *(const ushort8v*)&cs[rl][chunk * 8];
                *(ushort8v*)(base + (size_t)node * stride + coff + chunk * 8) = v;
            }
        }
    }
}

// ---------- K2: fused attention — FROZEN at its transaction-rate wall ----------
// Five structural variants (rounds 0-4) pinned at 97-107 µs; ~50M random 16-B
// gather transactions is the invariant cost. Body = round-3/4/6 proven form.
__global__ __launch_bounds__(256) void fused_attn_kernel(
    const float* __restrict__ eb,
    const unsigned short* __restrict__ Qb, const unsigned short* __restrict__ KVb,
    const int* __restrict__ cursor, const int2* __restrict__ slot2,
    float* __restrict__ alpha_out, float* __restrict__ h_out)
{
    const int wave = threadIdx.x >> 6;
    const int lane = threadIdx.x & 63;
    const int dst  = blockIdx.x * 4 + wave;
    if (dst >= N_NODES) return;
    const int es = lane >> 3;
    const int h  = lane & 7;

    // ---- epoch 0: independent head-of-chain loads ----
    const int degraw = cursor[dst];
    int sx = 0, sy = 0;
    if (lane < 32) {                                  // deg<=32 covers 99.98% of nodes
        const long long raw = __builtin_nontemporal_load(
            (const long long*)(slot2 + (size_t)dst * CAP + lane));
        sx = (int)(raw & 0xffffffffLL);
        sy = (int)(raw >> 32);
    }
    const unsigned short* qp = Qb + (size_t)dst * DIM + h * HD;
    const ushort8v q0 = __builtin_nontemporal_load((const ushort8v*)qp);
    const ushort8v q1 = __builtin_nontemporal_load((const ushort8v*)(qp + 8));

    const int degc = (degraw > CAP) ? CAP : degraw;
    if (degc == 0) {
        if (es == 0) {
            float4 z = {0.f, 0.f, 0.f, 0.f};
            float* hp = h_out + (size_t)dst * DIM + h * HD;
            #pragma unroll
            for (int d4 = 0; d4 < 4; ++d4) *(float4*)(hp + d4 * 4) = z;
        }
        return;
    }
    const int dm1 = degc - 1;
    const int G = (degc + 7) >> 3;                    // 1..8 groups of 8 edge slots

    float qf[16];
    #pragma unroll
    for (int j = 0; j < 8; ++j) { qf[j] = bf2f((unsigned short)q0[j]); qf[8 + j] = bf2f((unsigned short)q1[j]); }

    float s_stash[NGROUP_MAX];
    #pragma unroll
    for (int g = 0; g < NGROUP_MAX; ++g) s_stash[g] = -INFINITY;

    // ---- score pass: K gathers (cached; KVb is the reused array) + eb (nt) ----
    int srcs[4], ee[4];
    ushort8v ka[4], kb[4];
    float ebv[4];
    #pragma unroll
    for (int u = 0; u < 4; ++u) {
        if (u * 8 < degc) {                           // wave-uniform
            const int t  = u * 8 + es;
            const int tc = (t < dm1) ? t : dm1;       // <=31 here
            srcs[u] = __shfl(sx, tc);
            ee[u]   = __shfl(sy, tc);
            const unsigned short* kr = KVb + (size_t)srcs[u] * (2 * DIM) + h * HD;
            ka[u] = *(const ushort8v*)(kr);
            kb[u] = *(const ushort8v*)(kr + 8);
            ebv[u] = __builtin_nontemporal_load(eb + (size_t)ee[u] * NH + h);
        }
    }
    #pragma unroll
    for (int u = 0; u < 4; ++u) {
        if (u * 8 < degc) {
            const int t = u * 8 + es;
            float s = 0.f;
            #pragma unroll
            for (int j = 0; j < 8; ++j) {
                s = fmaf(bf2f((unsigned short)ka[u][j]), qf[j], s);
                s = fmaf(bf2f((unsigned short)kb[u][j]), qf[8 + j], s);
            }
            s_stash[u] = (t < degc) ? (s * 0.25f + ebv[u]) : -INFINITY;   // 1/sqrt(16)=0.25
        }
    }

    // ---- rare tail: deg > 32 (~0.02% of nodes), serial but correct ----
    const int2* sl = slot2 + (size_t)dst * CAP;
    #pragma unroll
    for (int g = 4; g < NGROUP_MAX; ++g) {
        if (g >= G) break;                            // wave-uniform
        const int t  = g * 8 + es;
        const int tc = (t < dm1) ? t : dm1;
        const int2 se = sl[tc];
        const unsigned short* kr = KVb + (size_t)se.x * (2 * DIM) + h * HD;
        const ushort8v k0 = *(const ushort8v*)(kr);
        const ushort8v k1 = *(const ushort8v*)(kr + 8);
        float s = 0.f;
        #pragma unroll
        for (int j = 0; j < 8; ++j) {
            s = fmaf(bf2f((unsigned short)k0[j]), qf[j], s);
            s = fmaf(bf2f((unsigned short)k1[j]), qf[8 + j], s);
        }
        s_stash[g] = (t < degc) ? (s * 0.25f + eb[(size_t)se.y * NH + h]) : -INFINITY;
    }

    // ---- single max reduction ----
    float m = s_stash[0];
    #pragma unroll
    for (int g = 1; g < NGROUP_MAX; ++g) m = fmaxf(m, s_stash[g]);
    m = fmaxf(m, __shfl_xor(m, 8));
    m = fmaxf(m, __shfl_xor(m, 16));
    m = fmaxf(m, __shfl_xor(m, 32));

    // ---- V pass: gathers issue together (srcs in regs), then exp+accumulate ----
    float pacc[16];
    #pragma unroll
    for (int d = 0; d < 16; ++d) pacc[d] = 0.f;
    float l = 0.f;

    ushort8v va[4], vb[4];
    #pragma unroll
    for (int u = 0; u < 4; ++u) {
        if (u * 8 < degc) {
            const unsigned short* vr = KVb + (size_t)srcs[u] * (2 * DIM) + DIM + h * HD;
            va[u] = *(const ushort8v*)(vr);
            vb[u] = *(const ushort8v*)(vr + 8);
        }
    }
    #pragma unroll
    for (int u = 0; u < 4; ++u) {
        if (u * 8 < degc) {
            const float ex = __expf(s_stash[u] - m);      // -INF slots -> 0
            s_stash[u] = ex;                              // stash for alpha pass
            l += ex;
            #pragma unroll
            for (int j = 0; j < 8; ++j) {
                pacc[j]     = fmaf(ex, bf2f((unsigned short)va[u][j]), pacc[j]);
                pacc[8 + j] = fmaf(ex, bf2f((unsigned short)vb[u][j]), pacc[8 + j]);
            }
        }
    }
    #pragma unroll
    for (int g = 4; g < NGROUP_MAX; ++g) {
        if (g >= G) break;
        const int t  = g * 8 + es;
        const int tc = (t < dm1) ? t : dm1;
        const int srcn = sl[tc].x;
        const unsigned short* vr = KVb + (size_t)srcn * (2 * DIM) + DIM + h * HD;
        const ushort8v v0 = *(const ushort8v*)(vr);
        const ushort8v v1 = *(const ushort8v*)(vr + 8);
        const float ex = __expf(s_stash[g] - m);
        s_stash[g] = ex;
        l += ex;
        #pragma unroll
        for (int j = 0; j < 8; ++j) {
            pacc[j]     = fmaf(ex, bf2f((unsigned short)v0[j]), pacc[j]);
            pacc[8 + j] = fmaf(ex, bf2f((unsigned short)v1[j]), pacc[8 + j]);
        }
    }

    // ---- reduce V accumulator and l across edge slots ----
    #pragma unroll
    for (int d = 0; d < 16; ++d) {
        pacc[d] += __shfl_xor(pacc[d], 8);
        pacc[d] += __shfl_xor(pacc[d], 16);
        pacc[d] += __shfl_xor(pacc[d], 32);
    }
    l += __shfl_xor(l, 8);
    l += __shfl_xor(l, 16);
    l += __shfl_xor(l, 32);
    const float inv_l = (l > 0.f) ? 1.f / l : 0.f;

    if (es == 0) {
        float* hp = h_out + (size_t)dst * DIM + h * HD;
        #pragma unroll
        for (int d4 = 0; d4 < 4; ++d4) {
            float4 o = { pacc[d4 * 4 + 0] * inv_l, pacc[d4 * 4 + 1] * inv_l,
                         pacc[d4 * 4 + 2] * inv_l, pacc[d4 * 4 + 3] * inv_l };
            *(float4*)(hp + d4 * 4) = o;
        }
    }

    // ---- alpha writes (cached; edge ids in regs for fast path) ----
    #pragma unroll
    for (int u = 0; u < 4; ++u) {
        if (u * 8 < degc) {
            const int t = u * 8 + es;
            if (t < degc)
                alpha_out[(size_t)ee[u] * NH + h] = s_stash[u] * inv_l;
        }
    }
    #pragma unroll
    for (int g = 4; g < NGROUP_MAX; ++g) {
        if (g >= G) break;
        const int t  = g * 8 + es;
        const int tc = (t < dm1) ? t : dm1;
        const int e = sl[tc].y;
        if (t < degc)
            alpha_out[(size_t)e * NH + h] = s_stash[g] * inv_l;
    }
}

extern "C" void kernel_launch(void* const* d_in, const int* in_sizes, int n_in,
                              void* d_out, int out_size, void* d_ws, size_t ws_size,
                              hipStream_t stream) {
    const float* x  = (const float*)d_in[0];
    const int*   ei = (const int*)d_in[1];
    const float* eb = (const float*)d_in[2];
    const float* WQ = (const float*)d_in[3];
    const float* bQ = (const float*)d_in[4];
    const float* WK = (const float*)d_in[5];
    const float* bK = (const float*)d_in[6];
    const float* WV = (const float*)d_in[7];
    const float* bV = (const float*)d_in[8];

    float* h_out     = (float*)d_out;                    // [N, 128] fp32
    float* alpha_out = (float*)d_out + N_NODES * DIM;    // [E, 8] fp32

    // workspace layout
    char* ws = (char*)d_ws;
    int*  cursor = (int*)ws;                                       // N
    int2* slot2  = (int2*)(ws + ((N_NODES * 4 + 15) & ~15));       // N*CAP int2 = 25.6 MB
    unsigned short* Qb  = (unsigned short*)(slot2 + (size_t)N_NODES * CAP);  // N*128 bf16
    unsigned short* KVb = Qb + (size_t)N_NODES * DIM;              // N*256 bf16
    // total ~ 0.2 + 25.6 + 12.8 + 25.6 ~= 64 MB

    hipMemsetAsync(cursor, 0, N_NODES * sizeof(int), stream);

    gemm_scatter_kernel<<<GEMM_BLOCKS + SCAT_BLOCKS, 256, 0, stream>>>(
        x, WQ, WK, WV, bQ, bK, bV, Qb, KVb, ei, cursor, slot2);

    fused_attn_kernel<<<(N_NODES + 3) / 4, 256, 0, stream>>>(
        eb, Qb, KVb, cursor, slot2, alpha_out, h_out);
}

// Round 8
// 234.844 us; speedup vs baseline: 1.0823x; 1.0823x over previous
//
#include <hip/hip_runtime.h>
#include <math.h>

#define N_NODES 50000
#define N_EDGES 800000
#define DIM 128
#define NH 8
#define HD 16
#define CAP 64                                           // max degree capacity (Poisson λ=16; P(>64)~1e-24)
#define NGROUP_MAX (CAP / 8)                             // 8
#define CSTRIDE 32                                       // cursor pad: 1 counter per 128-B line
#define N_RTILES (N_NODES / 16)                          // 3125
#define GEMM_BLOCKS ((N_RTILES + 15) / 16)               // 196: 4 row-tiles per wave (round-6 proven)
#define SCAT_BLOCKS ((N_EDGES / 4 + 255) / 256)          // 782 (4 edges/thread, int4 loads)
#define CONV_BLOCKS ((3 * DIM * DIM + 3 * DIM + 255) / 256)   // 194

typedef __attribute__((ext_vector_type(8))) short short8;
typedef __attribute__((ext_vector_type(8))) unsigned short ushort8v;
typedef __attribute__((ext_vector_type(4))) float floatx4;
typedef __attribute__((ext_vector_type(4))) int intx4;

// ---------- bf16 helpers ----------
__device__ __forceinline__ unsigned short f2bf(float f) {
    unsigned u = __float_as_uint(f);
    u += 0x7fffu + ((u >> 16) & 1u);        // round-to-nearest-even
    return (unsigned short)(u >> 16);
}
__device__ __forceinline__ float bf2f(unsigned short h) {
    return __uint_as_float((unsigned)h << 16);
}
__device__ __forceinline__ short8 pack_bf8(float4 lo, float4 hi) {
    short8 r;
    r[0] = (short)f2bf(lo.x); r[1] = (short)f2bf(lo.y);
    r[2] = (short)f2bf(lo.z); r[3] = (short)f2bf(lo.w);
    r[4] = (short)f2bf(hi.x); r[5] = (short)f2bf(hi.y);
    r[6] = (short)f2bf(hi.z); r[7] = (short)f2bf(hi.w);
    return r;
}

// ---------- K1: W/bias convert (cursor zero -> hipMemsetAsync) ----------
__global__ __launch_bounds__(256) void prep_kernel(
    const float* __restrict__ WQ, const float* __restrict__ WK, const float* __restrict__ WV,
    const float* __restrict__ bQ, const float* __restrict__ bK, const float* __restrict__ bV,
    unsigned short* __restrict__ Wb, float* __restrict__ bcat)
{
    const int i = blockIdx.x * 256 + threadIdx.x;
    if (i < 3 * DIM * DIM) {
        const float* W = (i < DIM * DIM) ? WQ : (i < 2 * DIM * DIM) ? WK : WV;
        Wb[i] = f2bf(W[i & (DIM * DIM - 1)]);
    } else if (i < 3 * DIM * DIM + 3 * DIM) {
        int j = i - 3 * DIM * DIM;
        const float* b = (j < DIM) ? bQ : (j < 2 * DIM) ? bK : bV;
        bcat[j] = b[j & (DIM - 1)];
    }
}

// ---------- K2: QKV MFMA GEMM (round-6 form: 4 rt/wave, LDS-transposed full-line
//              C stores)  ||  bucket scatter (line-padded cursor atomics) ----------
// Round-8 single delta: cursor stride 32 ints = 1 counter per 128-B line. Theory:
// scatter's 800k device-scope atomicAdd serialized on 32-counters-per-line at the
// coherence point (~40 µs of line-conflict serialization); padding gives every
// dst its own line -> full slice parallelism.
__global__ __launch_bounds__(256) void gemm_scatter_kernel(
    const float* __restrict__ x, const unsigned short* __restrict__ Wb,
    const float* __restrict__ bcat,
    unsigned short* __restrict__ Qb, unsigned short* __restrict__ KVb,
    const int* __restrict__ ei, int* __restrict__ cursor, int2* __restrict__ slot2)
{
    __shared__ unsigned short cstage[4][64][72];          // 36 KB/block, per-wave private

    if ((int)blockIdx.x >= GEMM_BLOCKS) {
        const int e0 = ((blockIdx.x - GEMM_BLOCKS) * 256 + threadIdx.x) * 4;
        if (e0 >= N_EDGES) return;                        // E%4==0 -> int4 safe
        const intx4 s4 = __builtin_nontemporal_load((const intx4*)(ei + e0));
        const intx4 d4 = __builtin_nontemporal_load((const intx4*)(ei + N_EDGES + e0));
        #pragma unroll
        for (int k = 0; k < 4; ++k) {
            const int dd = d4[k];
            const int pos = atomicAdd(cursor + (size_t)dd * CSTRIDE, 1);
            if (pos < CAP)
                slot2[(size_t)dd * CAP + pos] = make_int2(s4[k], e0 + k);
        }
        return;
    }

    const int wave = threadIdx.x >> 6;
    const int lane = threadIdx.x & 63;
    const int r    = lane & 15;
    const int quad = lane >> 4;
    const int rt0  = blockIdx.x * 16 + wave * 4;
    unsigned short (*cs)[72] = cstage[wave];

    short8 a[4][4];
    #pragma unroll
    for (int i = 0; i < 4; ++i) {
        int rt = rt0 + i; if (rt >= N_RTILES) rt = N_RTILES - 1;   // clamp (stores guarded)
        const float* xr = x + (size_t)(rt * 16 + r) * DIM + quad * 8;
        #pragma unroll
        for (int kk = 0; kk < 4; ++kk) {
            float4 lo = *(const float4*)(xr + kk * 32);
            float4 hi = *(const float4*)(xr + kk * 32 + 4);
            a[i][kk] = pack_bf8(lo, hi);
        }
    }

    const int chunk = lane & 7;                 // store-phase lane mapping
    const int rowg  = lane >> 3;

    for (int cg = 0; cg < 6; ++cg) {            // 6 groups of 4 col-tiles (64 cols)
        #pragma unroll
        for (int ci = 0; ci < 4; ++ci) {
            const int ct = cg * 4 + ci;
            const unsigned short* wr = Wb + (size_t)(ct * 16 + r) * DIM + quad * 8;
            short8 b0 = *(const short8*)(wr);
            short8 b1 = *(const short8*)(wr + 32);
            short8 b2 = *(const short8*)(wr + 64);
            short8 b3 = *(const short8*)(wr + 96);

            const float bias = bcat[ct * 16 + r];
            #pragma unroll
            for (int i = 0; i < 4; ++i) {
                floatx4 c = {0.f, 0.f, 0.f, 0.f};
                c = __builtin_amdgcn_mfma_f32_16x16x32_bf16(a[i][0], b0, c, 0, 0, 0);
                c = __builtin_amdgcn_mfma_f32_16x16x32_bf16(a[i][1], b1, c, 0, 0, 0);
                c = __builtin_amdgcn_mfma_f32_16x16x32_bf16(a[i][2], b2, c, 0, 0, 0);
                c = __builtin_amdgcn_mfma_f32_16x16x32_bf16(a[i][3], b3, c, 0, 0, 0);
                #pragma unroll
                for (int rr = 0; rr < 4; ++rr)
                    cs[i * 16 + quad * 4 + rr][ci * 16 + r] = f2bf(c[rr] + bias);
            }
        }

        // ---- flush: 64 rows x 64 cols as row-major full-line stores ----
        const int g0col = cg * 64;              // 0,64 -> Q; 128,192 -> K; 256,320 -> V
        const int m = g0col >> 7;               // 0=Q, 1=K, 2=V
        unsigned short* base;
        int stride, coff;
        if (m == 0) { base = Qb;  stride = DIM;     coff = g0col; }
        else        { base = KVb; stride = 2 * DIM; coff = (g0col & (DIM - 1)) + (m == 2 ? DIM : 0); }
        #pragma unroll
        for (int s = 0; s < 8; ++s) {
            const int rl = s * 8 + rowg;        // local row 0..63
            const int node = rt0 * 16 + rl;
            if (node < N_NODES) {
                const ushort8v v = *(const ushort8v*)&cs[rl][chunk * 8];
                *(ushort8v*)(base + (size_t)node * stride + coff + chunk * 8) = v;
            }
        }
    }
}

// ---------- K3: fused attention — FROZEN at its transaction-rate wall ----------
// Five structural variants (rounds 0-4) pinned at 97-107 µs; ~50M random 16-B
// gather transactions is the invariant cost. Body = round-3/4/6 proven form.
// Only delta: cursor read at stride CSTRIDE.
__global__ __launch_bounds__(256) void fused_attn_kernel(
    const float* __restrict__ eb,
    const unsigned short* __restrict__ Qb, const unsigned short* __restrict__ KVb,
    const int* __restrict__ cursor, const int2* __restrict__ slot2,
    float* __restrict__ alpha_out, float* __restrict__ h_out)
{
    const int wave = threadIdx.x >> 6;
    const int lane = threadIdx.x & 63;
    const int dst  = blockIdx.x * 4 + wave;
    if (dst >= N_NODES) return;
    const int es = lane >> 3;
    const int h  = lane & 7;

    // ---- epoch 0: independent head-of-chain loads ----
    const int degraw = cursor[(size_t)dst * CSTRIDE];
    int sx = 0, sy = 0;
    if (lane < 32) {                                  // deg<=32 covers 99.98% of nodes
        const long long raw = __builtin_nontemporal_load(
            (const long long*)(slot2 + (size_t)dst * CAP + lane));
        sx = (int)(raw & 0xffffffffLL);
        sy = (int)(raw >> 32);
    }
    const unsigned short* qp = Qb + (size_t)dst * DIM + h * HD;
    const ushort8v q0 = __builtin_nontemporal_load((const ushort8v*)qp);
    const ushort8v q1 = __builtin_nontemporal_load((const ushort8v*)(qp + 8));

    const int degc = (degraw > CAP) ? CAP : degraw;
    if (degc == 0) {
        if (es == 0) {
            float4 z = {0.f, 0.f, 0.f, 0.f};
            float* hp = h_out + (size_t)dst * DIM + h * HD;
            #pragma unroll
            for (int d4 = 0; d4 < 4; ++d4) *(float4*)(hp + d4 * 4) = z;
        }
        return;
    }
    const int dm1 = degc - 1;
    const int G = (degc + 7) >> 3;                    // 1..8 groups of 8 edge slots

    float qf[16];
    #pragma unroll
    for (int j = 0; j < 8; ++j) { qf[j] = bf2f((unsigned short)q0[j]); qf[8 + j] = bf2f((unsigned short)q1[j]); }

    float s_stash[NGROUP_MAX];
    #pragma unroll
    for (int g = 0; g < NGROUP_MAX; ++g) s_stash[g] = -INFINITY;

    // ---- score pass: K gathers (cached; KVb is the reused array) + eb (nt) ----
    int srcs[4], ee[4];
    ushort8v ka[4], kb[4];
    float ebv[4];
    #pragma unroll
    for (int u = 0; u < 4; ++u) {
        if (u * 8 < degc) {                           // wave-uniform
            const int t  = u * 8 + es;
            const int tc = (t < dm1) ? t : dm1;       // <=31 here
            srcs[u] = __shfl(sx, tc);
            ee[u]   = __shfl(sy, tc);
            const unsigned short* kr = KVb + (size_t)srcs[u] * (2 * DIM) + h * HD;
            ka[u] = *(const ushort8v*)(kr);
            kb[u] = *(const ushort8v*)(kr + 8);
            ebv[u] = __builtin_nontemporal_load(eb + (size_t)ee[u] * NH + h);
        }
    }
    #pragma unroll
    for (int u = 0; u < 4; ++u) {
        if (u * 8 < degc) {
            const int t = u * 8 + es;
            float s = 0.f;
            #pragma unroll
            for (int j = 0; j < 8; ++j) {
                s = fmaf(bf2f((unsigned short)ka[u][j]), qf[j], s);
                s = fmaf(bf2f((unsigned short)kb[u][j]), qf[8 + j], s);
            }
            s_stash[u] = (t < degc) ? (s * 0.25f + ebv[u]) : -INFINITY;   // 1/sqrt(16)=0.25
        }
    }

    // ---- rare tail: deg > 32 (~0.02% of nodes), serial but correct ----
    const int2* sl = slot2 + (size_t)dst * CAP;
    #pragma unroll
    for (int g = 4; g < NGROUP_MAX; ++g) {
        if (g >= G) break;                            // wave-uniform
        const int t  = g * 8 + es;
        const int tc = (t < dm1) ? t : dm1;
        const int2 se = sl[tc];
        const unsigned short* kr = KVb + (size_t)se.x * (2 * DIM) + h * HD;
        const ushort8v k0 = *(const ushort8v*)(kr);
        const ushort8v k1 = *(const ushort8v*)(kr + 8);
        float s = 0.f;
        #pragma unroll
        for (int j = 0; j < 8; ++j) {
            s = fmaf(bf2f((unsigned short)k0[j]), qf[j], s);
            s = fmaf(bf2f((unsigned short)k1[j]), qf[8 + j], s);
        }
        s_stash[g] = (t < degc) ? (s * 0.25f + eb[(size_t)se.y * NH + h]) : -INFINITY;
    }

    // ---- single max reduction ----
    float m = s_stash[0];
    #pragma unroll
    for (int g = 1; g < NGROUP_MAX; ++g) m = fmaxf(m, s_stash[g]);
    m = fmaxf(m, __shfl_xor(m, 8));
    m = fmaxf(m, __shfl_xor(m, 16));
    m = fmaxf(m, __shfl_xor(m, 32));

    // ---- V pass: gathers issue together (srcs in regs), then exp+accumulate ----
    float pacc[16];
    #pragma unroll
    for (int d = 0; d < 16; ++d) pacc[d] = 0.f;
    float l = 0.f;

    ushort8v va[4], vb[4];
    #pragma unroll
    for (int u = 0; u < 4; ++u) {
        if (u * 8 < degc) {
            const unsigned short* vr = KVb + (size_t)srcs[u] * (2 * DIM) + DIM + h * HD;
            va[u] = *(const ushort8v*)(vr);
            vb[u] = *(const ushort8v*)(vr + 8);
        }
    }
    #pragma unroll
    for (int u = 0; u < 4; ++u) {
        if (u * 8 < degc) {
            const float ex = __expf(s_stash[u] - m);      // -INF slots -> 0
            s_stash[u] = ex;                              // stash for alpha pass
            l += ex;
            #pragma unroll
            for (int j = 0; j < 8; ++j) {
                pacc[j]     = fmaf(ex, bf2f((unsigned short)va[u][j]), pacc[j]);
                pacc[8 + j] = fmaf(ex, bf2f((unsigned short)vb[u][j]), pacc[8 + j]);
            }
        }
    }
    #pragma unroll
    for (int g = 4; g < NGROUP_MAX; ++g) {
        if (g >= G) break;
        const int t  = g * 8 + es;
        const int tc = (t < dm1) ? t : dm1;
        const int srcn = sl[tc].x;
        const unsigned short* vr = KVb + (size_t)srcn * (2 * DIM) + DIM + h * HD;
        const ushort8v v0 = *(const ushort8v*)(vr);
        const ushort8v v1 = *(const ushort8v*)(vr + 8);
        const float ex = __expf(s_stash[g] - m);
        s_stash[g] = ex;
        l += ex;
        #pragma unroll
        for (int j = 0; j < 8; ++j) {
            pacc[j]     = fmaf(ex, bf2f((unsigned short)v0[j]), pacc[j]);
            pacc[8 + j] = fmaf(ex, bf2f((unsigned short)v1[j]), pacc[8 + j]);
        }
    }

    // ---- reduce V accumulator and l across edge slots ----
    #pragma unroll
    for (int d = 0; d < 16; ++d) {
        pacc[d] += __shfl_xor(pacc[d], 8);
        pacc[d] += __shfl_xor(pacc[d], 16);
        pacc[d] += __shfl_xor(pacc[d], 32);
    }
    l += __shfl_xor(l, 8);
    l += __shfl_xor(l, 16);
    l += __shfl_xor(l, 32);
    const float inv_l = (l > 0.f) ? 1.f / l : 0.f;

    if (es == 0) {
        float* hp = h_out + (size_t)dst * DIM + h * HD;
        #pragma unroll
        for (int d4 = 0; d4 < 4; ++d4) {
            float4 o = { pacc[d4 * 4 + 0] * inv_l, pacc[d4 * 4 + 1] * inv_l,
                         pacc[d4 * 4 + 2] * inv_l, pacc[d4 * 4 + 3] * inv_l };
            *(float4*)(hp + d4 * 4) = o;
        }
    }

    // ---- alpha writes (cached; edge ids in regs for fast path) ----
    #pragma unroll
    for (int u = 0; u < 4; ++u) {
        if (u * 8 < degc) {
            const int t = u * 8 + es;
            if (t < degc)
                alpha_out[(size_t)ee[u] * NH + h] = s_stash[u] * inv_l;
        }
    }
    #pragma unroll
    for (int g = 4; g < NGROUP_MAX; ++g) {
        if (g >= G) break;
        const int t  = g * 8 + es;
        const int tc = (t < dm1) ? t : dm1;
        const int e = sl[tc].y;
        if (t < degc)
            alpha_out[(size_t)e * NH + h] = s_stash[g] * inv_l;
    }
}

extern "C" void kernel_launch(void* const* d_in, const int* in_sizes, int n_in,
                              void* d_out, int out_size, void* d_ws, size_t ws_size,
                              hipStream_t stream) {
    const float* x  = (const float*)d_in[0];
    const int*   ei = (const int*)d_in[1];
    const float* eb = (const float*)d_in[2];
    const float* WQ = (const float*)d_in[3];
    const float* bQ = (const float*)d_in[4];
    const float* WK = (const float*)d_in[5];
    const float* bK = (const float*)d_in[6];
    const float* WV = (const float*)d_in[7];
    const float* bV = (const float*)d_in[8];

    float* h_out     = (float*)d_out;                    // [N, 128] fp32
    float* alpha_out = (float*)d_out + N_NODES * DIM;    // [E, 8] fp32

    // workspace layout
    char* ws = (char*)d_ws;
    int*  cursor = (int*)ws;                                       // N*CSTRIDE ints = 6.4 MB
    int2* slot2  = (int2*)(ws + (size_t)N_NODES * CSTRIDE * 4);    // N*CAP int2 = 25.6 MB
    char* after_slot = (char*)(slot2 + (size_t)N_NODES * CAP);
    unsigned short* Wb   = (unsigned short*)after_slot;            // 384*128 bf16
    float*          bcat = (float*)(Wb + 3 * DIM * DIM);           // 384 fp32
    unsigned short* Qb   = (unsigned short*)(bcat + 3 * DIM);      // N*128 bf16
    unsigned short* KVb  = Qb + (size_t)N_NODES * DIM;             // N*256 bf16
    // total ~ 6.4 + 25.6 + 0.1 + 12.8 + 25.6 ~= 71 MB

    hipMemsetAsync(cursor, 0, (size_t)N_NODES * CSTRIDE * 4, stream);

    prep_kernel<<<CONV_BLOCKS, 256, 0, stream>>>(WQ, WK, WV, bQ, bK, bV, Wb, bcat);

    gemm_scatter_kernel<<<GEMM_BLOCKS + SCAT_BLOCKS, 256, 0, stream>>>(
        x, Wb, bcat, Qb, KVb, ei, cursor, slot2);

    fused_attn_kernel<<<(N_NODES + 3) / 4, 256, 0, stream>>>(
        eb, Qb, KVb, cursor, slot2, alpha_out, h_out);
}